// Round 10
// baseline (1664.518 us; speedup 1.0000x reference)
//
#include <hip/hip_runtime.h>
#include <hip/hip_bf16.h>
#include <math.h>

// Problem dims (fixed by reference)
#define T_STEPS 512
#define BATCH   64
#define DIN     256
#define HID     1024
#define DOUT    256
#define NBLK    64      // rnn blocks: 4 row-groups x 16 col-groups

typedef __attribute__((ext_vector_type(8))) short    bf16x8;
typedef __attribute__((ext_vector_type(4))) float    f32x4;
typedef __attribute__((ext_vector_type(4))) int      i32x4;
typedef unsigned long long ull;

static __device__ __forceinline__ unsigned short f2bf(float f) {
    union { float f; unsigned u; } v; v.f = f;
    unsigned u = v.u;
    u += 0x7fff + ((u >> 16) & 1);   // round-to-nearest-even
    return (unsigned short)(u >> 16);
}
static __device__ __forceinline__ float bf2f(unsigned short h) {
    union { unsigned u; float f; } v; v.u = ((unsigned)h) << 16; return v.f;
}

// ---------------- convert Wx -> WxT bf16 ----------------
__global__ __launch_bounds__(256) void convert_wxt(const float* __restrict__ Wx,
                                                   unsigned short* __restrict__ wxtb) {
    int o = blockIdx.x * 256 + threadIdx.x;  // 262144 total
    int d = o & (DIN - 1);
    int j = o >> 8;
    wxtb[(size_t)j * DIN + d] = f2bf(Wx[(size_t)d * HID + j]);
}

// ---------------- pre = x @ Wx + b, in the rnn consumer's unit layout ----------
// 8-B unit for (t, block bx=r*16+c, wave w, lane=(q<<5|p<<4|m)):
//   4 bf16 = pre[t][row 16r+m][cols 64c+16w+8p+4q .. +4)
__global__ __launch_bounds__(256) void gemm_pre(const float* __restrict__ x,
                                                const unsigned short* __restrict__ wxtb,
                                                const float* __restrict__ bias,
                                                ull* __restrict__ pre_r) {
    __shared__ unsigned short ldsP[64 * 68];   // 64 rows x 64 cols bf16, stride 68
    int t = blockIdx.x, y = blockIdx.y;        // rows [64t..), cols [64y..)
    int wave = threadIdx.x >> 6, lane = threadIdx.x & 63;
    int l15 = lane & 15, lkq = lane >> 4;
    int nb = y * 64;

    f32x4 acc[4] = {};
    const float* aptr = x + (size_t)(t * 64 + wave * 16 + l15) * DIN + lkq * 8;
#pragma unroll
    for (int ks = 0; ks < 8; ++ks) {
        float4 f0 = *(const float4*)(aptr + ks * 32);
        float4 f1 = *(const float4*)(aptr + ks * 32 + 4);
        union { unsigned short s[8]; bf16x8 h; } ua;
        ua.s[0] = f2bf(f0.x); ua.s[1] = f2bf(f0.y); ua.s[2] = f2bf(f0.z); ua.s[3] = f2bf(f0.w);
        ua.s[4] = f2bf(f1.x); ua.s[5] = f2bf(f1.y); ua.s[6] = f2bf(f1.z); ua.s[7] = f2bf(f1.w);
#pragma unroll
        for (int nt = 0; nt < 4; ++nt) {
            bf16x8 b = *(const bf16x8*)(wxtb + (size_t)(nb + nt * 16 + l15) * DIN + ks * 32 + lkq * 8);
            acc[nt] = __builtin_amdgcn_mfma_f32_16x16x32_bf16(ua.h, b, acc[nt], 0, 0, 0);
        }
    }
#pragma unroll
    for (int nt = 0; nt < 4; ++nt) {
        float bb = bias[nb + nt * 16 + l15];
#pragma unroll
        for (int reg = 0; reg < 4; ++reg)
            ldsP[(16 * wave + lkq * 4 + reg) * 68 + nt * 16 + l15] = f2bf(acc[nt][reg] + bb);
    }
    __syncthreads();
#pragma unroll
    for (int i = 0; i < 4; ++i) {
        int u = threadIdx.x + 256 * i;            // 1024 units
        int rr = u >> 8, w2 = (u >> 6) & 3, ln = u & 63;
        int mm = ln & 15, pp = (ln >> 4) & 1, qq = ln >> 5;
        int row = rr * 16 + mm, coloff = 16 * w2 + 8 * pp + 4 * qq;
        ull v = *(const ull*)&ldsP[row * 68 + coloff];
        pre_r[((size_t)(t * 64 + rr * 16 + y) * 4 + w2) * 64 + ln] = v;
    }
}

// ---------------- persistent recurrence kernel ----------------
// 64 blocks x 256 threads. Block bx: c=bx&15 (cols), r=bx>>4 (rows 16r..16r+16).
// Wave w owns K range [256w..256w+256); Wh slice in REGISTERS.
// h storage: TAGGED 16B units. Logical chunk idx = r*2048 + ks*64 + lkq*16 + m
// (8 bf16 of h[16r+m][ks*32+lkq*8..+8)); stored as TWO 16B units at byte
// chunk*32 + q*16, each = [8B payload (4 bf16) | 4B tag=t | 4B pad], written by
// one global_store_dwordx4 sc0 sc1 (single-instruction 16B -> no tearing at
// MALL). Consumers poll the DATA: issue all 16 tagged loads (one vmcnt window),
// check 16 tags == t, retry. No flags, no release drain -> one RT per step.
// Triple-buffered; skew<=2 proof from R9 carries over (tag disambiguates).
__global__ __launch_bounds__(256, 1) void rnn_persistent(const float* __restrict__ Wh,
                                                         const ull* __restrict__ pre_r,
                                                         unsigned short* __restrict__ hbuf) {
    __shared__ float ldsR[2][4][16 * 68];   // [parity][wave][row*68+col] = 34816 B
    const int bx = blockIdx.x;
    const int c = bx & 15, r = bx >> 4;
    const int tid = threadIdx.x;
    const int w = tid >> 6, lane = tid & 63;
    const int l15 = lane & 15, lkq = lane >> 4;
    const int p = (lane >> 4) & 1, q = lane >> 5;
    const int m = l15;

    // One-time: B-fragments (Wh[k][col], k in wave range, cols 64c..64c+64) -> regs.
    bf16x8 bfr[8][4];
#pragma unroll
    for (int ksl = 0; ksl < 8; ++ksl)
#pragma unroll
        for (int nt = 0; nt < 4; ++nt) {
            union { unsigned short s[8]; bf16x8 h; } u;
            int k0 = w * 256 + ksl * 32 + lkq * 8;
            int col = c * 64 + nt * 16 + l15;
#pragma unroll
            for (int j = 0; j < 8; ++j)
                u.s[j] = f2bf(Wh[(size_t)(k0 + j) * HID + col]);
            bfr[ksl][nt] = u.h;
        }

    char* hb = (char*)hbuf;               // 3 buffers x 256 KB
    const char* hc = hb + 262144;         // read  at t=1 (tag 1)
    char*       hn = hb + 2 * 262144;     // write at t=1 (tag 2)
    char*       hx = hb;                  // write at t=2

    // This thread's h-store byte offset: chunk (ks=2c+(w>>1), lkq=2(w&1)+p, m), half q
    const size_t st_byte =
        ((size_t)r * 2048 + (size_t)(2 * c + (w >> 1)) * 64 + (2 * (w & 1) + p) * 16 + m) * 32
        + (size_t)q * 16;

    const ull* myPre = pre_r + ((size_t)bx * 4 + w) * 64 + lane;
#define PRE_AT(t) myPre[(size_t)(t) * 16384]

    // t = 0: h1 = tanh(pre0) (h0 == 0) -> buf1 with tag 1. Fire-and-forget.
    {
        union { ushort4 s; ull u; } pv; pv.u = PRE_AT(0);
        union { ushort4 s; unsigned d[2]; } hv;
        hv.s.x = f2bf(tanhf(bf2f(pv.s.x)));
        hv.s.y = f2bf(tanhf(bf2f(pv.s.y)));
        hv.s.z = f2bf(tanhf(bf2f(pv.s.z)));
        hv.s.w = f2bf(tanhf(bf2f(pv.s.w)));
        i32x4 sv; sv.x = (int)hv.d[0]; sv.y = (int)hv.d[1]; sv.z = 1; sv.w = 0;
        asm volatile("global_store_dwordx4 %0, %1, off sc0 sc1"
                     :: "v"((void*)(hb + 262144 + st_byte)), "v"(sv) : "memory");
    }

    ull pv_next = PRE_AT(1);

    for (int t = 1; t <= 510; ++t) {
        union { ushort4 s; ull u; } pvc; pvc.u = pv_next;
        if (t < 510) pv_next = PRE_AT(t + 1);

        // Tagged import: 16 x 16B sc1 loads, one vmcnt window; retry until all
        // 16 tags == t. (Data-as-flag: no producer drain, no separate poll.)
        i32x4 L[16];
        const char* abase = hc + ((size_t)r * 2048 + (size_t)(8 * w) * 64 + lane) * 32;
        {
            const int tt = t;
            for (;;) {
#pragma unroll
                for (int ksl = 0; ksl < 8; ++ksl) {
                    asm volatile("global_load_dwordx4 %0, %1, off sc0 sc1"
                                 : "=v"(L[2 * ksl])
                                 : "v"((const void*)(abase + (size_t)ksl * 2048)));
                    asm volatile("global_load_dwordx4 %0, %1, off sc0 sc1"
                                 : "=v"(L[2 * ksl + 1])
                                 : "v"((const void*)(abase + (size_t)ksl * 2048 + 16)));
                }
                asm volatile("s_waitcnt vmcnt(0)" ::: "memory");
                bool ok = true;
#pragma unroll
                for (int j = 0; j < 16; ++j) ok &= (L[j].z == tt);
                if (__ballot(ok) == ~0ull) break;
            }
        }
        __builtin_amdgcn_sched_barrier(0);

        f32x4 acc0 = {}, acc1 = {}, acc2 = {}, acc3 = {};
#pragma unroll
        for (int ksl = 0; ksl < 8; ++ksl) {
            union { i32x4 i; bf16x8 h; } av;
            av.i.x = L[2 * ksl].x;     av.i.y = L[2 * ksl].y;
            av.i.z = L[2 * ksl + 1].x; av.i.w = L[2 * ksl + 1].y;
            acc0 = __builtin_amdgcn_mfma_f32_16x16x32_bf16(av.h, bfr[ksl][0], acc0, 0, 0, 0);
            acc1 = __builtin_amdgcn_mfma_f32_16x16x32_bf16(av.h, bfr[ksl][1], acc1, 0, 0, 0);
            acc2 = __builtin_amdgcn_mfma_f32_16x16x32_bf16(av.h, bfr[ksl][2], acc2, 0, 0, 0);
            acc3 = __builtin_amdgcn_mfma_f32_16x16x32_bf16(av.h, bfr[ksl][3], acc3, 0, 0, 0);
        }

        // Partial sums -> parity LDS (row = lkq*4+reg, col = nt*16+l15).
        float* R = &ldsR[t & 1][w][0];
#pragma unroll
        for (int reg = 0; reg < 4; ++reg) {
            R[(lkq * 4 + reg) * 68 + l15]      = acc0[reg];
            R[(lkq * 4 + reg) * 68 + 16 + l15] = acc1[reg];
            R[(lkq * 4 + reg) * 68 + 32 + l15] = acc2[reg];
            R[(lkq * 4 + reg) * 68 + 48 + l15] = acc3[reg];
        }
        __syncthreads();   // the ONE barrier per step (cross-wave reduce)

        // Reduce across 4 waves, add pre, tanh, pack, tagged 16B store.
        const int coloff = 16 * w + 8 * p + 4 * q;
        f32x4 s;
        s  = *(const f32x4*)&ldsR[t & 1][0][m * 68 + coloff];
        s += *(const f32x4*)&ldsR[t & 1][1][m * 68 + coloff];
        s += *(const f32x4*)&ldsR[t & 1][2][m * 68 + coloff];
        s += *(const f32x4*)&ldsR[t & 1][3][m * 68 + coloff];
        union { ushort4 st; unsigned d[2]; } hv;
        hv.st.x = f2bf(tanhf(s[0] + bf2f(pvc.s.x)));
        hv.st.y = f2bf(tanhf(s[1] + bf2f(pvc.s.y)));
        hv.st.z = f2bf(tanhf(s[2] + bf2f(pvc.s.z)));
        hv.st.w = f2bf(tanhf(s[3] + bf2f(pvc.s.w)));
        i32x4 sv; sv.x = (int)hv.d[0]; sv.y = (int)hv.d[1]; sv.z = t + 1; sv.w = 0;
        asm volatile("global_store_dwordx4 %0, %1, off sc0 sc1"
                     :: "v"((void*)(hn + st_byte)), "v"(sv) : "memory");
        // No drain, no flag: consumers see the tag with the payload.

        // rotate triple buffer
        const char* tmp = hc; hc = hn; hn = hx; hx = (char*)tmp;
    }
#undef PRE_AT
    // h_511 (== H[-2]) is in buf1 (tagged layout); kernel end = device release.
}

// ---------------- y = h_final @ W2 + b2 (h in tagged 32B-chunk layout) ----------
__global__ __launch_bounds__(256) void out_gemm(const unsigned short* __restrict__ hfin,
                                                const float* __restrict__ W2,
                                                const float* __restrict__ b2,
                                                float* __restrict__ out) {
    int b = blockIdx.x;        // batch row, 64
    int j = threadIdx.x;       // out col, 256
    int r = b >> 4, m = b & 15;
    float acc = b2[j];
    const ull* hu = (const ull*)hfin;
    for (int ks = 0; ks < 32; ++ks) {
#pragma unroll
        for (int lkq = 0; lkq < 4; ++lkq) {
            size_t unit = (size_t)r * 2048 + (size_t)ks * 64 + lkq * 16 + m;
            int k0 = ks * 32 + lkq * 8;
            union { ull u; unsigned short s[4]; } p0, p1;
            p0.u = hu[unit * 4];       // q=0 payload: k0..k0+4
            p1.u = hu[unit * 4 + 2];   // q=1 payload: k0+4..k0+8
#pragma unroll
            for (int jj = 0; jj < 4; ++jj) {
                acc = fmaf(bf2f(p0.s[jj]), W2[(size_t)(k0 + jj) * DOUT + j], acc);
                acc = fmaf(bf2f(p1.s[jj]), W2[(size_t)(k0 + 4 + jj) * DOUT + j], acc);
            }
        }
    }
    out[(size_t)b * DOUT + j] = acc;
}

extern "C" void kernel_launch(void* const* d_in, const int* in_sizes, int n_in,
                              void* d_out, int out_size, void* d_ws, size_t ws_size,
                              hipStream_t stream) {
    const float* x  = (const float*)d_in[0];
    const float* Wx = (const float*)d_in[1];
    const float* Wh = (const float*)d_in[2];
    const float* b  = (const float*)d_in[3];
    const float* W2 = (const float*)d_in[4];
    const float* b2 = (const float*)d_in[5];
    float* out = (float*)d_out;

    // workspace carve (~66 MB). 0xAA poison guarantees stale tags never == t.
    char* ws = (char*)d_ws;
    unsigned short* hbuf  = (unsigned short*)(ws + 4096);            // 3 x 256 KB tagged
    unsigned short* wxtb  = (unsigned short*)(ws + 4096 + 786432);   // 0.5 MB
    ull*            pre_r = (ull*)(ws + 4096 + 786432 + 524288);     // 64 MB

    convert_wxt<<<1024, 256, 0, stream>>>(Wx, wxtb);
    gemm_pre<<<dim3(512, 16), 256, 0, stream>>>(x, wxtb, b, pre_r);
    rnn_persistent<<<NBLK, 256, 0, stream>>>(Wh, pre_r, hbuf);
    out_gemm<<<64, 256, 0, stream>>>((unsigned short*)((char*)hbuf + 262144), W2, b2, out);
}